// Round 9
// baseline (285.321 us; speedup 1.0000x reference)
//
#include <hip/hip_runtime.h>

#define S_LEN 2048
#define NB    2
#define EMB   1024
#define NH    16
#define HD    64

typedef __bf16 bf16_t;
typedef bf16_t bf16x8 __attribute__((ext_vector_type(8)));
typedef bf16_t bf16x4v __attribute__((ext_vector_type(4)));
typedef float  f32x4  __attribute__((ext_vector_type(4)));
typedef float  f32x16 __attribute__((ext_vector_type(16)));

#define L2E 1.44269504f   // log2(e)

// async global->LDS, 16B per lane; LDS dest = wave-uniform base + lane*16
__device__ __forceinline__ void g2l16(const void* g, void* l) {
    auto gp = reinterpret_cast<const unsigned int __attribute__((address_space(1)))*>(
        reinterpret_cast<uintptr_t>(g));
    auto lp = reinterpret_cast<unsigned int __attribute__((address_space(3)))*>(
        reinterpret_cast<uintptr_t>(l));
    __builtin_amdgcn_global_load_lds(gp, lp, 16, 0, 0);
}

// ---------------------------------------------------------------------------
// Fused fp32 -> bf16 cast of x, w_tor, in_proj_w, out_w (float4 granularity).
// ---------------------------------------------------------------------------
__global__ __launch_bounds__(256) void cast4_f32_bf16(
    const float* __restrict__ s0, bf16_t* __restrict__ d0,
    const float* __restrict__ s1, bf16_t* __restrict__ d1,
    const float* __restrict__ s2, bf16_t* __restrict__ d2,
    const float* __restrict__ s3, bf16_t* __restrict__ d3)
{
    long i = (long)blockIdx.x * 256 + threadIdx.x;
    const float* s; bf16_t* d; long off;
    if (i < 1048576)      { s = s0; d = d0; off = i; }
    else if (i < 1310720) { s = s1; d = d1; off = i - 1048576; }
    else if (i < 2097152) { s = s2; d = d2; off = i - 1310720; }
    else                  { s = s3; d = d3; off = i - 2097152; }
    float4 v = ((const float4*)s)[off];
    bf16x4v o;
    o[0] = (bf16_t)v.x; o[1] = (bf16_t)v.y; o[2] = (bf16_t)v.z; o[3] = (bf16_t)v.w;
    *(bf16x4v*)(d + off * 4) = o;
}

// ---------------------------------------------------------------------------
// bf16 MFMA GEMM, double-buffered prefetch K-loop (1 barrier/iter).
// C(M,N) = A(M,K) @ W(N,K)^T + bias(N). TM=128, TN in {64,128}, BK=32.
// MODE: 0 = fp32 out, 1 = bf16 out, 2 = qkv head-layout epilogue:
//   Q pre-scaled by 0.125*log2e; K natural [b,h,s,d]; V written directly
//   transposed [b,h,d,s] (natural column order).
// ---------------------------------------------------------------------------
template<int TN, int MODE>
__global__ __launch_bounds__(256) void gemm_bt_bf16(
    const bf16_t* __restrict__ A, const bf16_t* __restrict__ W,
    const float* __restrict__ bias, void* __restrict__ Cout,
    bf16_t* __restrict__ Qp, bf16_t* __restrict__ Kp, bf16_t* __restrict__ Vtp,
    int M, int N, int K)
{
    constexpr int MB = (TN == 128) ? 4 : 2;
    __shared__ __align__(16) bf16_t As[2][128 * 32];
    __shared__ __align__(16) bf16_t Bs[2][TN * 32];

    const int tid  = threadIdx.x;
    const int lane = tid & 63;
    const int w    = tid >> 6;
    const int lm   = lane & 15;
    const int lq   = lane >> 4;
    const long m0  = (long)blockIdx.y * 128;
    const long n0  = (long)blockIdx.x * TN;
    const int wm0  = (TN == 128) ? (w >> 1) * 64 : w * 32;
    const int wn0  = (TN == 128) ? (w & 1) * 64 : 0;

    f32x4 acc[MB][4];
#pragma unroll
    for (int i = 0; i < MB; ++i)
#pragma unroll
        for (int j = 0; j < 4; ++j) acc[i][j] = (f32x4){0.f, 0.f, 0.f, 0.f};

    auto stage = [&](int k0, int buf) {
        bf16_t* asb = &As[buf][0];
        bf16_t* bsb = &Bs[buf][0];
#pragma unroll
        for (int j = 0; j < 2; ++j) {
            int a   = (w * 2 + j) * 64 + lane;
            int row = a >> 2;
            int c   = (a & 3) ^ ((row >> 1) & 3);
            g2l16(A + (m0 + row) * K + k0 + c * 8, asb + (w * 2 + j) * 512);
        }
#pragma unroll
        for (int j = 0; j < TN / 64; ++j) {
            int a   = (w * (TN / 64) + j) * 64 + lane;
            int row = a >> 2;
            int c   = (a & 3) ^ ((row >> 1) & 3);
            g2l16(W + (n0 + row) * K + k0 + c * 8, bsb + (w * (TN / 64) + j) * 512);
        }
    };

    stage(0, 0);
    for (int k0 = 0; k0 < K; k0 += 32) {
        const int cur = (k0 >> 5) & 1;
        asm volatile("s_waitcnt vmcnt(0)" ::: "memory");
        __syncthreads();
        if (k0 + 32 < K) stage(k0 + 32, cur ^ 1);

        bf16x8 af[MB], bfr[4];
#pragma unroll
        for (int mb = 0; mb < MB; ++mb) {
            int r = wm0 + mb * 16 + lm;
            af[mb] = *(const bf16x8*)&As[cur][r * 32 + ((lq ^ ((r >> 1) & 3)) << 3)];
        }
#pragma unroll
        for (int nb = 0; nb < 4; ++nb) {
            int r = wn0 + nb * 16 + lm;
            bfr[nb] = *(const bf16x8*)&Bs[cur][r * 32 + ((lq ^ ((r >> 1) & 3)) << 3)];
        }
#pragma unroll
        for (int mb = 0; mb < MB; ++mb)
#pragma unroll
            for (int nb = 0; nb < 4; ++nb)
                acc[mb][nb] = __builtin_amdgcn_mfma_f32_16x16x32_bf16(
                    af[mb], bfr[nb], acc[mb][nb], 0, 0, 0);
    }

    // ---- epilogue ----
    float b4[4];
#pragma unroll
    for (int nb = 0; nb < 4; ++nb) b4[nb] = bias[n0 + wn0 + nb * 16 + lm];

#pragma unroll
    for (int mb = 0; mb < MB; ++mb) {
#pragma unroll
        for (int r = 0; r < 4; ++r) {
            long m = m0 + wm0 + mb * 16 + lq * 4 + r;
#pragma unroll
            for (int nb = 0; nb < 4; ++nb) {
                int n   = (int)n0 + wn0 + nb * 16 + lm;
                float v = acc[mb][nb][r] + b4[nb];
                if (MODE == 0) {
                    ((float*)Cout)[m * N + n] = v;
                } else if (MODE == 1) {
                    ((bf16_t*)Cout)[m * N + n] = (bf16_t)v;
                } else {
                    int sec  = n >> 10;                 // uniform per block
                    int nloc = n & 1023;
                    int h    = nloc >> 6;
                    int d    = nloc & 63;
                    int s    = (int)(m >> 1), b = (int)(m & 1);
                    int bh   = b * 16 + h;
                    if (sec == 0) {
                        Qp[((size_t)(bh * S_LEN + s)) * 64 + d] =
                            (bf16_t)(v * (0.125f * L2E));
                    } else if (sec == 1) {
                        Kp[((size_t)(bh * S_LEN + s)) * 64 + d] = (bf16_t)v;
                    } else {
                        Vtp[((size_t)(bh * 64 + d)) * S_LEN + s] = (bf16_t)v;
                    }
                }
            }
        }
    }
}

// ---------------------------------------------------------------------------
// MFMA flash attention, 32x32x16 S^T formulation, no K/V LDS staging.
// Block = 64 q-rows x all keys; 4 waves = (kh, qh) quadrants.
// S^T = K·Q^T (A=K-frags from global, B=Q-frags held in regs): C-layout puts
// q in lanes (col) and key in regs (row) -> exp'd P packs as b64 rows into a
// shared, half-chunk-swizzled Ps[q][k] (swizzle h ^= q&15, 2-way max).
// PV: O = P·V with A=P (b64 reads, k-contiguous), B=V^T rows from global.
// One barrier/iter (Ps double-buffered). Fixed-max exp2 softmax, deferred l.
// ---------------------------------------------------------------------------
__global__ __launch_bounds__(256, 4) void attn_mfma(
    const bf16_t* __restrict__ Qb, const bf16_t* __restrict__ Kb,
    const bf16_t* __restrict__ Vtb, bf16_t* __restrict__ O)
{
    __shared__ __align__(16) bf16_t Ps[2][64 * 64];   // 16 KB

    const int tid  = threadIdx.x;
    const int lane = tid & 63;
    const int w    = tid >> 6;
    const int kh   = w & 1;     // key half (S^T) == d half (PV)
    const int qh   = w >> 1;    // q half
    const int bh   = blockIdx.x >> 5;
    const int qt   = blockIdx.x & 31;
    const int l5   = lane & 31;
    const int hi   = lane >> 5;
    const int qm   = l5 & 15;   // q & 15 (swizzle key)

    // Q B-frags (B[k=d][n=q]), held across the whole loop
    const bf16_t* qrow = Qb + ((size_t)bh * S_LEN + qt * 64 + qh * 32 + l5) * 64 + hi * 8;
    bf16x8 qf[4];
#pragma unroll
    for (int ds = 0; ds < 4; ++ds) qf[ds] = *(const bf16x8*)(qrow + ds * 16);

    // K rows: key = kt*64 + kh*32 + l5 (advance 64 rows/iter)
    const bf16_t* kptr = Kb + ((size_t)bh * S_LEN + kh * 32 + l5) * 64 + hi * 8;
    // V^T rows: d = kh*32 + l5; s advances 64/iter
    const bf16_t* vptr = Vtb + ((size_t)bh * 64 + kh * 32 + l5) * S_LEN + hi * 8;

    // Ps lane-fixed addresses (element offset = h'*4, h' = h ^ (q&15))
    bf16_t* pw[4];
#pragma unroll
    for (int rq = 0; rq < 4; ++rq)
        pw[rq] = &Ps[0][(qh * 32 + l5) * 64 + (((kh * 8 + 2 * rq + hi) ^ qm) << 2)];
    const bf16_t* pr[8];
#pragma unroll
    for (int ks = 0; ks < 4; ++ks)
#pragma unroll
        for (int e = 0; e < 2; ++e)
            pr[ks * 2 + e] = &Ps[0][(qh * 32 + l5) * 64 + (((ks * 4 + hi * 2 + e) ^ qm) << 2)];

    f32x16 oacc;
#pragma unroll
    for (int i = 0; i < 16; ++i) oacc[i] = 0.f;
    float plsum = 0.f;

    for (int kt = 0; kt < 32; ++kt) {
        const int pofs = (kt & 1) * 4096;

        // ---- K A-frags from global ----
        bf16x8 kf[4];
#pragma unroll
        for (int ds = 0; ds < 4; ++ds) kf[ds] = *(const bf16x8*)(kptr + ds * 16);

        // ---- S^T = K · Q^T (log2 domain) ----
        f32x16 sacc;
#pragma unroll
        for (int i = 0; i < 16; ++i) sacc[i] = 0.f;
#pragma unroll
        for (int ds = 0; ds < 4; ++ds)
            sacc = __builtin_amdgcn_mfma_f32_32x32x16_bf16(kf[ds], qf[ds], sacc, 0, 0, 0);

        // ---- toroidal bias: only near-diagonal K-tiles ----
        int ktd = (kt - qt) & 31;
        if (ktd <= 1 || ktd == 31) {
            int qrow_g = qt * 64 + qh * 32 + l5;
#pragma unroll
            for (int r = 0; r < 16; ++r) {
                int key  = kt * 64 + kh * 32 + (r & 3) + 8 * (r >> 2) + 4 * hi;
                int diff = (key - qrow_g) & (S_LEN - 1);
                if (diff <= 1 || diff == S_LEN - 1) sacc[r] += L2E;
            }
        }

        // ---- p = 2^S; pack 4 consecutive keys -> one b64 per rq ----
#pragma unroll
        for (int rq = 0; rq < 4; ++rq) {
            bf16x4v pk;
#pragma unroll
            for (int e2 = 0; e2 < 4; ++e2) {
                float p = __builtin_amdgcn_exp2f(sacc[rq * 4 + e2]);
                plsum += p;
                pk[e2] = (bf16_t)p;
            }
            *(bf16x4v*)(pw[rq] + pofs) = pk;
        }

        // ---- V B-frags from global (issued before the barrier) ----
        bf16x8 vf[4];
#pragma unroll
        for (int ks = 0; ks < 4; ++ks) vf[ks] = *(const bf16x8*)(vptr + ks * 16);

        __syncthreads();   // Ps quadrants complete

        // ---- PV: O(q x d) += P · V ----
#pragma unroll
        for (int ks = 0; ks < 4; ++ks) {
            bf16x4v lo  = *(const bf16x4v*)(pr[ks * 2 + 0] + pofs);
            bf16x4v hi4 = *(const bf16x4v*)(pr[ks * 2 + 1] + pofs);
            bf16x8 pf;
#pragma unroll
            for (int j = 0; j < 4; ++j) { pf[j] = lo[j]; pf[4 + j] = hi4[j]; }
            oacc = __builtin_amdgcn_mfma_f32_32x32x16_bf16(pf, vf[ks], oacc, 0, 0, 0);
        }

        kptr += 64 * 64;
        vptr += 64;
    }

    // ---- l reduction: lanes L and L^32 share q; then cross-(kh) via LDS ----
    plsum += __shfl_xor(plsum, 32, 64);
    __syncthreads();                          // last PV reads of Ps done
    float* Lsum = (float*)&Ps[0][0];          // reuse: [2][64]
    if (lane < 32) Lsum[kh * 64 + qh * 32 + lane] = plsum;
    __syncthreads();

    float inv[4][4];
#pragma unroll
    for (int rq = 0; rq < 4; ++rq) {
        f32x4 a = *(const f32x4*)&Lsum[qh * 32 + 8 * rq + 4 * hi];
        f32x4 c = *(const f32x4*)&Lsum[64 + qh * 32 + 8 * rq + 4 * hi];
#pragma unroll
        for (int e2 = 0; e2 < 4; ++e2) inv[rq][e2] = 1.0f / (a[e2] + c[e2]);
    }

    const int b = bh >> 4, h = bh & 15;
#pragma unroll
    for (int r = 0; r < 16; ++r) {
        int qrel = (r & 3) + 8 * (r >> 2) + 4 * hi;
        int s = qt * 64 + qh * 32 + qrel;
        O[((size_t)(s * NB + b)) * EMB + h * 64 + kh * 32 + l5] =
            (bf16_t)(oacc[r] * inv[r >> 2][r & 3]);
    }
}

// ---------------------------------------------------------------------------
// Workspace map (42 MB):
//   [ 0, 8) xb -> reused as Qb | [ 8,10) wtorb | [10,16) ipwb | [16,18) outwb
//   [18,26) xtb -> reused as Ob | [26,34) Kb | [34,42) Vtb (natural cols)
// ---------------------------------------------------------------------------
extern "C" void kernel_launch(void* const* d_in, const int* in_sizes, int n_in,
                              void* d_out, int out_size, void* d_ws, size_t ws_size,
                              hipStream_t stream)
{
    const float* x         = (const float*)d_in[0];
    const float* w_tor     = (const float*)d_in[1];
    const float* b_tor     = (const float*)d_in[2];
    const float* in_proj_w = (const float*)d_in[3];
    const float* in_proj_b = (const float*)d_in[4];
    const float* out_w     = (const float*)d_in[5];
    const float* out_b     = (const float*)d_in[6];
    float* out = (float*)d_out;

    const int M = S_LEN * NB;   // 4096

    char* base = (char*)d_ws;
    bf16_t* xb    = (bf16_t*)(base);
    bf16_t* wtorb = (bf16_t*)(base + ( 8ull << 20));
    bf16_t* ipwb  = (bf16_t*)(base + (10ull << 20));
    bf16_t* outwb = (bf16_t*)(base + (16ull << 20));
    bf16_t* xtb   = (bf16_t*)(base + (18ull << 20));
    bf16_t* Kb    = (bf16_t*)(base + (26ull << 20));
    bf16_t* Vtb   = (bf16_t*)(base + (34ull << 20));
    bf16_t* Qb    = xb;    // alias: xb dead once GEMM1 has run
    bf16_t* Ob    = xtb;   // alias: xtb dead once GEMM2 has run

    cast4_f32_bf16<<<dim3(9216), 256, 0, stream>>>(
        x, xb, w_tor, wtorb, in_proj_w, ipwb, out_w, outwb);

    gemm_bt_bf16<64, 1><<<dim3(EMB / 64, M / 128), 256, 0, stream>>>(
        xb, wtorb, b_tor, xtb, nullptr, nullptr, nullptr, M, EMB, EMB);

    gemm_bt_bf16<128, 2><<<dim3(3 * EMB / 128, M / 128), 256, 0, stream>>>(
        xtb, ipwb, in_proj_b, nullptr, Qb, Kb, Vtb, M, 3 * EMB, EMB);

    attn_mfma<<<dim3(32 * 32), 256, 0, stream>>>(Qb, Kb, Vtb, Ob);

    gemm_bt_bf16<64, 0><<<dim3(EMB / 64, M / 128), 256, 0, stream>>>(
        Ob, outwb, out_b, out, nullptr, nullptr, nullptr, M, EMB, EMB);
}

// Round 10
// 218.939 us; speedup vs baseline: 1.3032x; 1.3032x over previous
//
#include <hip/hip_runtime.h>

#define S_LEN 2048
#define NB    2
#define EMB   1024
#define NH    16
#define HD    64

typedef __bf16 bf16_t;
typedef bf16_t bf16x8 __attribute__((ext_vector_type(8)));
typedef bf16_t bf16x4v __attribute__((ext_vector_type(4)));
typedef float  f32x4  __attribute__((ext_vector_type(4)));
typedef float  f32x16 __attribute__((ext_vector_type(16)));

#define L2E 1.44269504f   // log2(e)

// async global->LDS, 16B per lane; LDS dest = wave-uniform base + lane*16
__device__ __forceinline__ void g2l16(const void* g, void* l) {
    auto gp = reinterpret_cast<const unsigned int __attribute__((address_space(1)))*>(
        reinterpret_cast<uintptr_t>(g));
    auto lp = reinterpret_cast<unsigned int __attribute__((address_space(3)))*>(
        reinterpret_cast<uintptr_t>(l));
    __builtin_amdgcn_global_load_lds(gp, lp, 16, 0, 0);
}

// ---------------------------------------------------------------------------
// Fused fp32 -> bf16 cast of x, w_tor, in_proj_w, out_w (float4 granularity).
// ---------------------------------------------------------------------------
__global__ __launch_bounds__(256) void cast4_f32_bf16(
    const float* __restrict__ s0, bf16_t* __restrict__ d0,
    const float* __restrict__ s1, bf16_t* __restrict__ d1,
    const float* __restrict__ s2, bf16_t* __restrict__ d2,
    const float* __restrict__ s3, bf16_t* __restrict__ d3)
{
    long i = (long)blockIdx.x * 256 + threadIdx.x;
    const float* s; bf16_t* d; long off;
    if (i < 1048576)      { s = s0; d = d0; off = i; }
    else if (i < 1310720) { s = s1; d = d1; off = i - 1048576; }
    else if (i < 2097152) { s = s2; d = d2; off = i - 1310720; }
    else                  { s = s3; d = d3; off = i - 2097152; }
    float4 v = ((const float4*)s)[off];
    bf16x4v o;
    o[0] = (bf16_t)v.x; o[1] = (bf16_t)v.y; o[2] = (bf16_t)v.z; o[3] = (bf16_t)v.w;
    *(bf16x4v*)(d + off * 4) = o;
}

// ---------------------------------------------------------------------------
// bf16 MFMA GEMM, double-buffered prefetch K-loop (1 barrier/iter).
// C(M,N) = A(M,K) @ W(N,K)^T + bias(N). TM=128, TN in {64,128}, BK=32.
// MODE: 0 = fp32 out, 1 = bf16 out, 2 = qkv head-layout epilogue:
//   Q pre-scaled by 0.125*log2e; K natural [b,h,s,d]; V written directly
//   transposed [b,h,d,s] (natural column order).
// ---------------------------------------------------------------------------
template<int TN, int MODE>
__global__ __launch_bounds__(256) void gemm_bt_bf16(
    const bf16_t* __restrict__ A, const bf16_t* __restrict__ W,
    const float* __restrict__ bias, void* __restrict__ Cout,
    bf16_t* __restrict__ Qp, bf16_t* __restrict__ Kp, bf16_t* __restrict__ Vtp,
    int M, int N, int K)
{
    constexpr int MB = (TN == 128) ? 4 : 2;
    __shared__ __align__(16) bf16_t As[2][128 * 32];
    __shared__ __align__(16) bf16_t Bs[2][TN * 32];

    const int tid  = threadIdx.x;
    const int lane = tid & 63;
    const int w    = tid >> 6;
    const int lm   = lane & 15;
    const int lq   = lane >> 4;
    const long m0  = (long)blockIdx.y * 128;
    const long n0  = (long)blockIdx.x * TN;
    const int wm0  = (TN == 128) ? (w >> 1) * 64 : w * 32;
    const int wn0  = (TN == 128) ? (w & 1) * 64 : 0;

    f32x4 acc[MB][4];
#pragma unroll
    for (int i = 0; i < MB; ++i)
#pragma unroll
        for (int j = 0; j < 4; ++j) acc[i][j] = (f32x4){0.f, 0.f, 0.f, 0.f};

    auto stage = [&](int k0, int buf) {
        bf16_t* asb = &As[buf][0];
        bf16_t* bsb = &Bs[buf][0];
#pragma unroll
        for (int j = 0; j < 2; ++j) {
            int a   = (w * 2 + j) * 64 + lane;
            int row = a >> 2;
            int c   = (a & 3) ^ ((row >> 1) & 3);
            g2l16(A + (m0 + row) * K + k0 + c * 8, asb + (w * 2 + j) * 512);
        }
#pragma unroll
        for (int j = 0; j < TN / 64; ++j) {
            int a   = (w * (TN / 64) + j) * 64 + lane;
            int row = a >> 2;
            int c   = (a & 3) ^ ((row >> 1) & 3);
            g2l16(W + (n0 + row) * K + k0 + c * 8, bsb + (w * (TN / 64) + j) * 512);
        }
    };

    stage(0, 0);
    for (int k0 = 0; k0 < K; k0 += 32) {
        const int cur = (k0 >> 5) & 1;
        asm volatile("s_waitcnt vmcnt(0)" ::: "memory");
        __syncthreads();
        if (k0 + 32 < K) stage(k0 + 32, cur ^ 1);

        bf16x8 af[MB], bfr[4];
#pragma unroll
        for (int mb = 0; mb < MB; ++mb) {
            int r = wm0 + mb * 16 + lm;
            af[mb] = *(const bf16x8*)&As[cur][r * 32 + ((lq ^ ((r >> 1) & 3)) << 3)];
        }
#pragma unroll
        for (int nb = 0; nb < 4; ++nb) {
            int r = wn0 + nb * 16 + lm;
            bfr[nb] = *(const bf16x8*)&Bs[cur][r * 32 + ((lq ^ ((r >> 1) & 3)) << 3)];
        }
#pragma unroll
        for (int mb = 0; mb < MB; ++mb)
#pragma unroll
            for (int nb = 0; nb < 4; ++nb)
                acc[mb][nb] = __builtin_amdgcn_mfma_f32_16x16x32_bf16(
                    af[mb], bfr[nb], acc[mb][nb], 0, 0, 0);
    }

    // ---- epilogue ----
    float b4[4];
#pragma unroll
    for (int nb = 0; nb < 4; ++nb) b4[nb] = bias[n0 + wn0 + nb * 16 + lm];

#pragma unroll
    for (int mb = 0; mb < MB; ++mb) {
#pragma unroll
        for (int r = 0; r < 4; ++r) {
            long m = m0 + wm0 + mb * 16 + lq * 4 + r;
#pragma unroll
            for (int nb = 0; nb < 4; ++nb) {
                int n   = (int)n0 + wn0 + nb * 16 + lm;
                float v = acc[mb][nb][r] + b4[nb];
                if (MODE == 0) {
                    ((float*)Cout)[m * N + n] = v;
                } else if (MODE == 1) {
                    ((bf16_t*)Cout)[m * N + n] = (bf16_t)v;
                } else {
                    int sec  = n >> 10;                 // uniform per block
                    int nloc = n & 1023;
                    int h    = nloc >> 6;
                    int d    = nloc & 63;
                    int s    = (int)(m >> 1), b = (int)(m & 1);
                    int bh   = b * 16 + h;
                    if (sec == 0) {
                        Qp[((size_t)(bh * S_LEN + s)) * 64 + d] =
                            (bf16_t)(v * (0.125f * L2E));
                    } else if (sec == 1) {
                        Kp[((size_t)(bh * S_LEN + s)) * 64 + d] = (bf16_t)v;
                    } else {
                        Vtp[((size_t)(bh * 64 + d)) * S_LEN + s] = (bf16_t)v;
                    }
                }
            }
        }
    }
}

// ---------------------------------------------------------------------------
// MFMA flash attention: 32x32x16 S^T formulation + round-8-style dbuf
// global_load_lds staging (the verified latency-hiding skeleton).
// Block = 128 q-rows (4 waves x 32 q), grid = 32 bh x 16 qtiles = 512.
// Per iter: stage next K/V tile (64 keys) into LDS; wave computes
// S^T = K·Q^T for both 32-key halves (A=K from LDS, B=Q in regs; C puts
// q in lanes, keys in regs), exp2 -> packed b64 writes into WAVE-PRIVATE
// Ps (16B-slot XOR swizzle), then PV (A=P b128 reads, B=V^T from LDS).
// One barrier/iter; P needs no barrier (wave-private, lgkm-ordered).
// Fragment layouts verified end-to-end in round 9; staging verified round 8.
// ---------------------------------------------------------------------------
__global__ __launch_bounds__(256, 2) void attn_mfma(
    const bf16_t* __restrict__ Qb, const bf16_t* __restrict__ Kb,
    const bf16_t* __restrict__ Vtb, bf16_t* __restrict__ O)
{
    __shared__ __align__(16) bf16_t Ks[2][64 * 64];    // 16 KB
    __shared__ __align__(16) bf16_t Vts[2][64 * 64];   // 16 KB
    __shared__ __align__(16) bf16_t Ps[4][32 * 64];    // 16 KB, wave-private

    const int tid  = threadIdx.x;
    const int lane = tid & 63;
    const int w    = tid >> 6;
    const int bh   = blockIdx.x >> 4;
    const int qt   = blockIdx.x & 15;
    const int l5   = lane & 31;
    const int hi   = lane >> 5;
    const int sr   = lane >> 3;                 // staging sub-row 0..7
    const int chunk = (lane & 7) ^ (sr & 7);    // staging swizzled chunk
    const int sw   = l5 & 7;                    // slot-swizzle key (row&7)

    // Q B-frags (B[n=q][k=d]), q = qt*128 + w*32 + l5, held in regs
    const bf16_t* qrow = Qb + ((size_t)bh * S_LEN + qt * 128 + w * 32 + l5) * 64 + hi * 8;
    bf16x8 qf[4];
#pragma unroll
    for (int ds = 0; ds < 4; ++ds) qf[ds] = *(const bf16x8*)(qrow + ds * 16);

    f32x16 oacc[2];
#pragma unroll
    for (int dh = 0; dh < 2; ++dh)
#pragma unroll
        for (int i = 0; i < 16; ++i) oacc[dh][i] = 0.f;
    float plsum = 0.f;

    auto stageKV = [&](int kt, int buf) {
        bf16_t* ksb = &Ks[buf][0];
        bf16_t* vsb = &Vts[buf][0];
        const bf16_t* kg = Kb + ((size_t)bh * S_LEN + kt * 64) * 64;
        g2l16(kg + (size_t)(w * 16 + sr) * 64 + chunk * 8,     ksb + (w * 16) * 64);
        g2l16(kg + (size_t)(w * 16 + 8 + sr) * 64 + chunk * 8, ksb + (w * 16 + 8) * 64);
        const bf16_t* vg = Vtb + (size_t)bh * 64 * S_LEN + kt * 64;
        g2l16(vg + (size_t)(w * 16 + sr) * S_LEN + chunk * 8,     vsb + (w * 16) * 64);
        g2l16(vg + (size_t)(w * 16 + 8 + sr) * S_LEN + chunk * 8, vsb + (w * 16 + 8) * 64);
    };

    stageKV(0, 0);
    for (int kt = 0; kt < 32; ++kt) {
        const int cur = kt & 1;
        asm volatile("s_waitcnt vmcnt(0)" ::: "memory");
        __syncthreads();
        if (kt < 31) stageKV(kt + 1, cur ^ 1);

        // ---- S^T = K·Q^T per key half (log2 domain) ----
        f32x16 sacc[2];
#pragma unroll
        for (int kh = 0; kh < 2; ++kh) {
#pragma unroll
            for (int i = 0; i < 16; ++i) sacc[kh][i] = 0.f;
            int row = kh * 32 + l5;
#pragma unroll
            for (int ds = 0; ds < 4; ++ds) {
                bf16x8 kf = *(const bf16x8*)&Ks[cur][row * 64 + (((2 * ds + hi) ^ sw) << 3)];
                sacc[kh] = __builtin_amdgcn_mfma_f32_32x32x16_bf16(kf, qf[ds], sacc[kh], 0, 0, 0);
            }
        }

        // ---- toroidal bias: only near-diagonal K-tiles ----
        int ktd = (kt - 2 * qt) & 31;
        if (ktd <= 2 || ktd == 31) {
            int q = qt * 128 + w * 32 + l5;
#pragma unroll
            for (int kh = 0; kh < 2; ++kh)
#pragma unroll
                for (int r = 0; r < 16; ++r) {
                    int key  = kt * 64 + kh * 32 + (r & 3) + 8 * (r >> 2) + 4 * hi;
                    int diff = (key - q) & (S_LEN - 1);
                    if (diff <= 1 || diff == S_LEN - 1) sacc[kh][r] += L2E;
                }
        }

        // ---- p = 2^S; packed b64 writes into wave-private Ps ----
#pragma unroll
        for (int kh = 0; kh < 2; ++kh)
#pragma unroll
            for (int g = 0; g < 4; ++g) {
                bf16x4v pk;
#pragma unroll
                for (int e = 0; e < 4; ++e) {
                    float p = __builtin_amdgcn_exp2f(sacc[kh][g * 4 + e]);
                    plsum += p;
                    pk[e] = (bf16_t)p;
                }
                int slot = (kh * 4 + g) ^ sw;
                *(bf16x4v*)&Ps[w][l5 * 64 + slot * 8 + hi * 4] = pk;
            }

        // ---- PV: O[q][d] += P·V (P same-wave, lgkm-ordered) ----
        bf16x8 pf[4];
#pragma unroll
        for (int ks = 0; ks < 4; ++ks)
            pf[ks] = *(const bf16x8*)&Ps[w][l5 * 64 + (((2 * ks + hi) ^ sw) << 3)];
#pragma unroll
        for (int dh = 0; dh < 2; ++dh) {
            int d = dh * 32 + l5;
#pragma unroll
            for (int ks = 0; ks < 4; ++ks) {
                bf16x8 vf = *(const bf16x8*)&Vts[cur][d * 64 + (((2 * ks + hi) ^ sw) << 3)];
                oacc[dh] = __builtin_amdgcn_mfma_f32_32x32x16_bf16(pf[ks], vf, oacc[dh], 0, 0, 0);
            }
        }
    }

    // ---- l: lane + lane^32 hold the two key-halves of row q=l5 ----
    plsum += __shfl_xor(plsum, 32, 64);
    float* Lw = (float*)&Ps[w][0];            // reuse wave-private region
    if (hi == 0) Lw[l5] = plsum;

    float inv16[16];
#pragma unroll
    for (int g = 0; g < 4; ++g) {
        f32x4 lv = *(const f32x4*)&Lw[8 * g + 4 * hi];
#pragma unroll
        for (int e = 0; e < 4; ++e) inv16[g * 4 + e] = 1.0f / lv[e];
    }

    const int b = bh >> 4, h = bh & 15;
#pragma unroll
    for (int dh = 0; dh < 2; ++dh)
#pragma unroll
        for (int r = 0; r < 16; ++r) {
            int qrel = (r & 3) + 8 * (r >> 2) + 4 * hi;
            int s = qt * 128 + w * 32 + qrel;
            O[((size_t)(s * NB + b)) * EMB + h * 64 + dh * 32 + l5] =
                (bf16_t)(oacc[dh][r] * inv16[r]);
        }
}

// ---------------------------------------------------------------------------
// Workspace map (42 MB):
//   [ 0, 8) xb -> reused as Qb | [ 8,10) wtorb | [10,16) ipwb | [16,18) outwb
//   [18,26) xtb -> reused as Ob | [26,34) Kb | [34,42) Vtb (natural cols)
// ---------------------------------------------------------------------------
extern "C" void kernel_launch(void* const* d_in, const int* in_sizes, int n_in,
                              void* d_out, int out_size, void* d_ws, size_t ws_size,
                              hipStream_t stream)
{
    const float* x         = (const float*)d_in[0];
    const float* w_tor     = (const float*)d_in[1];
    const float* b_tor     = (const float*)d_in[2];
    const float* in_proj_w = (const float*)d_in[3];
    const float* in_proj_b = (const float*)d_in[4];
    const float* out_w     = (const float*)d_in[5];
    const float* out_b     = (const float*)d_in[6];
    float* out = (float*)d_out;

    const int M = S_LEN * NB;   // 4096

    char* base = (char*)d_ws;
    bf16_t* xb    = (bf16_t*)(base);
    bf16_t* wtorb = (bf16_t*)(base + ( 8ull << 20));
    bf16_t* ipwb  = (bf16_t*)(base + (10ull << 20));
    bf16_t* outwb = (bf16_t*)(base + (16ull << 20));
    bf16_t* xtb   = (bf16_t*)(base + (18ull << 20));
    bf16_t* Kb    = (bf16_t*)(base + (26ull << 20));
    bf16_t* Vtb   = (bf16_t*)(base + (34ull << 20));
    bf16_t* Qb    = xb;    // alias: xb dead once GEMM1 has run
    bf16_t* Ob    = xtb;   // alias: xtb dead once GEMM2 has run

    cast4_f32_bf16<<<dim3(9216), 256, 0, stream>>>(
        x, xb, w_tor, wtorb, in_proj_w, ipwb, out_w, outwb);

    gemm_bt_bf16<64, 1><<<dim3(EMB / 64, M / 128), 256, 0, stream>>>(
        xb, wtorb, b_tor, xtb, nullptr, nullptr, nullptr, M, EMB, EMB);

    gemm_bt_bf16<128, 2><<<dim3(3 * EMB / 128, M / 128), 256, 0, stream>>>(
        xtb, ipwb, in_proj_b, nullptr, Qb, Kb, Vtb, M, 3 * EMB, EMB);

    attn_mfma<<<dim3(32 * 16), 256, 0, stream>>>(Qb, Kb, Vtb, Ob);

    gemm_bt_bf16<64, 0><<<dim3(EMB / 64, M / 128), 256, 0, stream>>>(
        Ob, outwb, out_b, out, nullptr, nullptr, nullptr, M, EMB, EMB);
}

// Round 11
// 216.726 us; speedup vs baseline: 1.3165x; 1.0102x over previous
//
#include <hip/hip_runtime.h>

#define S_LEN 2048
#define NB    2
#define EMB   1024
#define NH    16
#define HD    64

typedef __bf16 bf16_t;
typedef bf16_t bf16x8 __attribute__((ext_vector_type(8)));
typedef bf16_t bf16x4v __attribute__((ext_vector_type(4)));
typedef float  f32x4  __attribute__((ext_vector_type(4)));
typedef float  f32x16 __attribute__((ext_vector_type(16)));

#define L2E 1.44269504f   // log2(e)

// async global->LDS, 16B per lane; LDS dest = wave-uniform base + lane*16
__device__ __forceinline__ void g2l16(const void* g, void* l) {
    auto gp = reinterpret_cast<const unsigned int __attribute__((address_space(1)))*>(
        reinterpret_cast<uintptr_t>(g));
    auto lp = reinterpret_cast<unsigned int __attribute__((address_space(3)))*>(
        reinterpret_cast<uintptr_t>(l));
    __builtin_amdgcn_global_load_lds(gp, lp, 16, 0, 0);
}

// ---------------------------------------------------------------------------
// Fused fp32 -> bf16 cast of x, w_tor, in_proj_w, out_w (float4 granularity).
// ---------------------------------------------------------------------------
__global__ __launch_bounds__(256) void cast4_f32_bf16(
    const float* __restrict__ s0, bf16_t* __restrict__ d0,
    const float* __restrict__ s1, bf16_t* __restrict__ d1,
    const float* __restrict__ s2, bf16_t* __restrict__ d2,
    const float* __restrict__ s3, bf16_t* __restrict__ d3)
{
    long i = (long)blockIdx.x * 256 + threadIdx.x;
    const float* s; bf16_t* d; long off;
    if (i < 1048576)      { s = s0; d = d0; off = i; }
    else if (i < 1310720) { s = s1; d = d1; off = i - 1048576; }
    else if (i < 2097152) { s = s2; d = d2; off = i - 1310720; }
    else                  { s = s3; d = d3; off = i - 2097152; }
    float4 v = ((const float4*)s)[off];
    bf16x4v o;
    o[0] = (bf16_t)v.x; o[1] = (bf16_t)v.y; o[2] = (bf16_t)v.z; o[3] = (bf16_t)v.w;
    *(bf16x4v*)(d + off * 4) = o;
}

// ---------------------------------------------------------------------------
// bf16 MFMA GEMM, double-buffered prefetch K-loop (1 barrier/iter).
// C(M,N) = A(M,K) @ W(N,K)^T + bias(N). TM=128, TN in {64,128}, BK=32.
// MODE: 0 = fp32 out, 1 = bf16 out, 2 = qkv head-layout epilogue:
//   Q pre-scaled by 0.125*log2e; K natural [b,h,s,d]; V written directly
//   transposed [b,h,d,s] (natural column order).
// ---------------------------------------------------------------------------
template<int TN, int MODE>
__global__ __launch_bounds__(256) void gemm_bt_bf16(
    const bf16_t* __restrict__ A, const bf16_t* __restrict__ W,
    const float* __restrict__ bias, void* __restrict__ Cout,
    bf16_t* __restrict__ Qp, bf16_t* __restrict__ Kp, bf16_t* __restrict__ Vtp,
    int M, int N, int K)
{
    constexpr int MB = (TN == 128) ? 4 : 2;
    __shared__ __align__(16) bf16_t As[2][128 * 32];
    __shared__ __align__(16) bf16_t Bs[2][TN * 32];

    const int tid  = threadIdx.x;
    const int lane = tid & 63;
    const int w    = tid >> 6;
    const int lm   = lane & 15;
    const int lq   = lane >> 4;
    const long m0  = (long)blockIdx.y * 128;
    const long n0  = (long)blockIdx.x * TN;
    const int wm0  = (TN == 128) ? (w >> 1) * 64 : w * 32;
    const int wn0  = (TN == 128) ? (w & 1) * 64 : 0;

    f32x4 acc[MB][4];
#pragma unroll
    for (int i = 0; i < MB; ++i)
#pragma unroll
        for (int j = 0; j < 4; ++j) acc[i][j] = (f32x4){0.f, 0.f, 0.f, 0.f};

    auto stage = [&](int k0, int buf) {
        bf16_t* asb = &As[buf][0];
        bf16_t* bsb = &Bs[buf][0];
#pragma unroll
        for (int j = 0; j < 2; ++j) {
            int a   = (w * 2 + j) * 64 + lane;
            int row = a >> 2;
            int c   = (a & 3) ^ ((row >> 1) & 3);
            g2l16(A + (m0 + row) * K + k0 + c * 8, asb + (w * 2 + j) * 512);
        }
#pragma unroll
        for (int j = 0; j < TN / 64; ++j) {
            int a   = (w * (TN / 64) + j) * 64 + lane;
            int row = a >> 2;
            int c   = (a & 3) ^ ((row >> 1) & 3);
            g2l16(W + (n0 + row) * K + k0 + c * 8, bsb + (w * (TN / 64) + j) * 512);
        }
    };

    stage(0, 0);
    for (int k0 = 0; k0 < K; k0 += 32) {
        const int cur = (k0 >> 5) & 1;
        asm volatile("s_waitcnt vmcnt(0)" ::: "memory");
        __syncthreads();
        if (k0 + 32 < K) stage(k0 + 32, cur ^ 1);

        bf16x8 af[MB], bfr[4];
#pragma unroll
        for (int mb = 0; mb < MB; ++mb) {
            int r = wm0 + mb * 16 + lm;
            af[mb] = *(const bf16x8*)&As[cur][r * 32 + ((lq ^ ((r >> 1) & 3)) << 3)];
        }
#pragma unroll
        for (int nb = 0; nb < 4; ++nb) {
            int r = wn0 + nb * 16 + lm;
            bfr[nb] = *(const bf16x8*)&Bs[cur][r * 32 + ((lq ^ ((r >> 1) & 3)) << 3)];
        }
#pragma unroll
        for (int mb = 0; mb < MB; ++mb)
#pragma unroll
            for (int nb = 0; nb < 4; ++nb)
                acc[mb][nb] = __builtin_amdgcn_mfma_f32_16x16x32_bf16(
                    af[mb], bfr[nb], acc[mb][nb], 0, 0, 0);
    }

    // ---- epilogue ----
    float b4[4];
#pragma unroll
    for (int nb = 0; nb < 4; ++nb) b4[nb] = bias[n0 + wn0 + nb * 16 + lm];

#pragma unroll
    for (int mb = 0; mb < MB; ++mb) {
#pragma unroll
        for (int r = 0; r < 4; ++r) {
            long m = m0 + wm0 + mb * 16 + lq * 4 + r;
#pragma unroll
            for (int nb = 0; nb < 4; ++nb) {
                int n   = (int)n0 + wn0 + nb * 16 + lm;
                float v = acc[mb][nb][r] + b4[nb];
                if (MODE == 0) {
                    ((float*)Cout)[m * N + n] = v;
                } else if (MODE == 1) {
                    ((bf16_t*)Cout)[m * N + n] = (bf16_t)v;
                } else {
                    int sec  = n >> 10;                 // uniform per block
                    int nloc = n & 1023;
                    int h    = nloc >> 6;
                    int d    = nloc & 63;
                    int s    = (int)(m >> 1), b = (int)(m & 1);
                    int bh   = b * 16 + h;
                    if (sec == 0) {
                        Qp[((size_t)(bh * S_LEN + s)) * 64 + d] =
                            (bf16_t)(v * (0.125f * L2E));
                    } else if (sec == 1) {
                        Kp[((size_t)(bh * S_LEN + s)) * 64 + d] = (bf16_t)v;
                    } else {
                        Vtp[((size_t)(bh * 64 + d)) * S_LEN + s] = (bf16_t)v;
                    }
                }
            }
        }
    }
}

// ---------------------------------------------------------------------------
// MFMA flash attention: 32x32x16 S^T formulation, dbuf g2l staging, with
// CHUNK-MAJOR LDS layouts: slot(row, chunk) = chunk*64 + row for K/V tiles,
// chunk*32 + q for P. This makes every b128 fragment read a run of
// consecutive 16B slots across lanes (the canonical conflict-free pattern;
// round-10's row-major 32-row x 2-chunk reads measured 7.3M conflicts).
// Staging gathers are strided (lane = row, fixed chunk); the 8 per-tile
// instructions reuse the same 64 cache lines -> L1-served after first.
// Block = 128 q (4 waves x 32 q), grid 512. One barrier/iter; P wave-private.
// ---------------------------------------------------------------------------
__global__ __launch_bounds__(256, 2) void attn_mfma(
    const bf16_t* __restrict__ Qb, const bf16_t* __restrict__ Kb,
    const bf16_t* __restrict__ Vtb, bf16_t* __restrict__ O)
{
    __shared__ __align__(16) bf16_t Ks[2][8 * 512];    // 16 KB, chunk-major
    __shared__ __align__(16) bf16_t Vts[2][8 * 512];   // 16 KB, chunk-major
    __shared__ __align__(16) bf16_t Ps[4][8 * 256];    // 16 KB, wave-private

    const int tid  = threadIdx.x;
    const int lane = tid & 63;
    const int w    = tid >> 6;
    const int bh   = blockIdx.x >> 4;
    const int qt   = blockIdx.x & 15;
    const int l5   = lane & 31;
    const int hi   = lane >> 5;

    // Q B-frags (B[n=q][k=d]), q = qt*128 + w*32 + l5, held in regs
    const bf16_t* qrow = Qb + ((size_t)bh * S_LEN + qt * 128 + w * 32 + l5) * 64 + hi * 8;
    bf16x8 qf[4];
#pragma unroll
    for (int ds = 0; ds < 4; ++ds) qf[ds] = *(const bf16x8*)(qrow + ds * 16);

    f32x16 oacc[2];
#pragma unroll
    for (int dh = 0; dh < 2; ++dh)
#pragma unroll
        for (int i = 0; i < 16; ++i) oacc[dh][i] = 0.f;
    float plsum = 0.f;

    // chunk-major staging: instruction c stages chunk c of all 64 rows.
    auto stageKV = [&](int kt, int buf) {
        bf16_t* ksb = &Ks[buf][0];
        bf16_t* vsb = &Vts[buf][0];
        const bf16_t* kg = Kb + ((size_t)bh * S_LEN + kt * 64) * 64;
        const bf16_t* vg = Vtb + (size_t)bh * 64 * S_LEN + kt * 64;
#pragma unroll
        for (int j = 0; j < 2; ++j) {
            int c = w * 2 + j;
            g2l16(kg + (size_t)lane * 64 + c * 8,    ksb + c * 512);
            g2l16(vg + (size_t)lane * S_LEN + c * 8, vsb + c * 512);
        }
    };

    stageKV(0, 0);
    for (int kt = 0; kt < 32; ++kt) {
        const int cur = kt & 1;
        asm volatile("s_waitcnt vmcnt(0)" ::: "memory");
        __syncthreads();
        if (kt < 31) stageKV(kt + 1, cur ^ 1);

        // ---- S^T = K·Q^T per key half (log2 domain) ----
        f32x16 sacc[2];
#pragma unroll
        for (int kh = 0; kh < 2; ++kh) {
#pragma unroll
            for (int i = 0; i < 16; ++i) sacc[kh][i] = 0.f;
#pragma unroll
            for (int ds = 0; ds < 4; ++ds) {
                bf16x8 kf = *(const bf16x8*)&Ks[cur][(2 * ds + hi) * 512 + (kh * 32 + l5) * 8];
                sacc[kh] = __builtin_amdgcn_mfma_f32_32x32x16_bf16(kf, qf[ds], sacc[kh], 0, 0, 0);
            }
        }

        // ---- toroidal bias: only near-diagonal K-tiles ----
        int ktd = (kt - 2 * qt) & 31;
        if (ktd <= 2 || ktd == 31) {
            int q = qt * 128 + w * 32 + l5;
#pragma unroll
            for (int kh = 0; kh < 2; ++kh)
#pragma unroll
                for (int r = 0; r < 16; ++r) {
                    int key  = kt * 64 + kh * 32 + (r & 3) + 8 * (r >> 2) + 4 * hi;
                    int diff = (key - q) & (S_LEN - 1);
                    if (diff <= 1 || diff == S_LEN - 1) sacc[kh][r] += L2E;
                }
        }

        // ---- p = 2^S; packed b64 writes, chunk-major Ps ----
#pragma unroll
        for (int kh = 0; kh < 2; ++kh)
#pragma unroll
            for (int g = 0; g < 4; ++g) {
                bf16x4v pk;
#pragma unroll
                for (int e = 0; e < 4; ++e) {
                    float p = __builtin_amdgcn_exp2f(sacc[kh][g * 4 + e]);
                    plsum += p;
                    pk[e] = (bf16_t)p;
                }
                // keys base kh*32+8g+4hi -> chunk kh*4+g, half hi
                *(bf16x4v*)&Ps[w][(kh * 4 + g) * 256 + l5 * 8 + hi * 4] = pk;
            }

        // ---- PV: O[q][d] += P·V (P same-wave, lgkm-ordered) ----
        bf16x8 pf[4];
#pragma unroll
        for (int ks = 0; ks < 4; ++ks)
            pf[ks] = *(const bf16x8*)&Ps[w][(2 * ks + hi) * 256 + l5 * 8];
#pragma unroll
        for (int dh = 0; dh < 2; ++dh) {
#pragma unroll
            for (int ks = 0; ks < 4; ++ks) {
                bf16x8 vf = *(const bf16x8*)&Vts[cur][(2 * ks + hi) * 512 + (dh * 32 + l5) * 8];
                oacc[dh] = __builtin_amdgcn_mfma_f32_32x32x16_bf16(pf[ks], vf, oacc[dh], 0, 0, 0);
            }
        }
    }

    // ---- l: lane + lane^32 hold the two key-halves of row q=l5 ----
    plsum += __shfl_xor(plsum, 32, 64);
    float* Lw = (float*)&Ps[w][0];            // reuse wave-private region
    if (hi == 0) Lw[l5] = plsum;

    float inv16[16];
#pragma unroll
    for (int g = 0; g < 4; ++g) {
        f32x4 lv = *(const f32x4*)&Lw[8 * g + 4 * hi];
#pragma unroll
        for (int e = 0; e < 4; ++e) inv16[g * 4 + e] = 1.0f / lv[e];
    }

    const int b = bh >> 4, h = bh & 15;
#pragma unroll
    for (int dh = 0; dh < 2; ++dh)
#pragma unroll
        for (int r = 0; r < 16; ++r) {
            int qrel = (r & 3) + 8 * (r >> 2) + 4 * hi;
            int s = qt * 128 + w * 32 + qrel;
            O[((size_t)(s * NB + b)) * EMB + h * 64 + dh * 32 + l5] =
                (bf16_t)(oacc[dh][r] * inv16[r]);
        }
}

// ---------------------------------------------------------------------------
// Workspace map (42 MB):
//   [ 0, 8) xb -> reused as Qb | [ 8,10) wtorb | [10,16) ipwb | [16,18) outwb
//   [18,26) xtb -> reused as Ob | [26,34) Kb | [34,42) Vtb (natural cols)
// ---------------------------------------------------------------------------
extern "C" void kernel_launch(void* const* d_in, const int* in_sizes, int n_in,
                              void* d_out, int out_size, void* d_ws, size_t ws_size,
                              hipStream_t stream)
{
    const float* x         = (const float*)d_in[0];
    const float* w_tor     = (const float*)d_in[1];
    const float* b_tor     = (const float*)d_in[2];
    const float* in_proj_w = (const float*)d_in[3];
    const float* in_proj_b = (const float*)d_in[4];
    const float* out_w     = (const float*)d_in[5];
    const float* out_b     = (const float*)d_in[6];
    float* out = (float*)d_out;

    const int M = S_LEN * NB;   // 4096

    char* base = (char*)d_ws;
    bf16_t* xb    = (bf16_t*)(base);
    bf16_t* wtorb = (bf16_t*)(base + ( 8ull << 20));
    bf16_t* ipwb  = (bf16_t*)(base + (10ull << 20));
    bf16_t* outwb = (bf16_t*)(base + (16ull << 20));
    bf16_t* xtb   = (bf16_t*)(base + (18ull << 20));
    bf16_t* Kb    = (bf16_t*)(base + (26ull << 20));
    bf16_t* Vtb   = (bf16_t*)(base + (34ull << 20));
    bf16_t* Qb    = xb;    // alias: xb dead once GEMM1 has run
    bf16_t* Ob    = xtb;   // alias: xtb dead once GEMM2 has run

    cast4_f32_bf16<<<dim3(9216), 256, 0, stream>>>(
        x, xb, w_tor, wtorb, in_proj_w, ipwb, out_w, outwb);

    gemm_bt_bf16<64, 1><<<dim3(EMB / 64, M / 128), 256, 0, stream>>>(
        xb, wtorb, b_tor, xtb, nullptr, nullptr, nullptr, M, EMB, EMB);

    gemm_bt_bf16<128, 2><<<dim3(3 * EMB / 128, M / 128), 256, 0, stream>>>(
        xtb, ipwb, in_proj_b, nullptr, Qb, Kb, Vtb, M, 3 * EMB, EMB);

    attn_mfma<<<dim3(32 * 16), 256, 0, stream>>>(Qb, Kb, Vtb, Ob);

    gemm_bt_bf16<64, 0><<<dim3(EMB / 64, M / 128), 256, 0, stream>>>(
        Ob, outwb, out_b, out, nullptr, nullptr, nullptr, M, EMB, EMB);
}